// Round 19
// baseline (93.847 us; speedup 1.0000x reference)
//
#include <hip/hip_runtime.h>
#include <hip/hip_bf16.h>

typedef unsigned short u16;
typedef unsigned int u32;
typedef __attribute__((ext_vector_type(8))) short short8;
typedef __attribute__((ext_vector_type(4))) float f32x4;

#define H 8
#define N 384
#define D 32
#define CIN 256
#define HNN (H * N * N)
#define SCALER 0.17677669529663687f
#define EPS 1e-9f

// workspace float offsets
#define PROJ_OFF 0u              // 5*H*N*D = 491520: a,b,c,vj,vk as [5][H][N][D]
#define S_OFF    491520u         // 3*H*N*N: t=0 XT[k][j], t=1 Y[k][i], t=2 Z[i][j]
#define VJT_OFF  4030464u        // H*D*N = 98304: vj transposed [h][d][n]
#define VKT_OFF  4128768u        // H*D*N
#define NUM_OFF  4233224u        // H*N*D
#define DEN_OFF  4331528u        // H*N
#define XBF_OFF  4334600u        // ushort[H*N*N]: X packed in MFMA-frag order
#define ZBF_OFF  4924424u        // ushort[H*N*N] (Z bf16, row-major)
#define KEYS_OFF 5514248u        // u32 keys: mXrowK[H*N], mYcolK[H*N], mZK[H*N] (memset 0)
#define LBF_OFF  5523464u        // u16[3*H*N*D]: bf16 copies of a,b,c for scores MFMA

__device__ inline float bf2f(u16 u) {
    union { unsigned int x; float f; } c; c.x = ((unsigned int)u) << 16; return c.f;
}
__device__ inline u16 f2bf(float f) {
    unsigned int x = __float_as_uint(f);
    return (u16)((x + 0x7FFFu + ((x >> 16) & 1u)) >> 16);
}
// order-preserving float->uint key (exact; atomicMax-able); 0 is below all keys
__device__ inline u32 fkey(float f) {
    u32 u = __float_as_uint(f);
    return (u >> 31) ? ~u : (u | 0x80000000u);
}
__device__ inline float fkey_dec(u32 k) {
    return (k >> 31) ? __uint_as_float(k ^ 0x80000000u) : __uint_as_float(~k);
}

// ---------------- K1: projection GEMM  wx[n,m] = sum_k hs[n,k]*W[m,k] ----------------
// also emits bf16 copies of a,b,c (s<3) for the MFMA scores kernel
__global__ __launch_bounds__(256) void proj_kernel(const float* __restrict__ hs,
                                                   const float* __restrict__ W,
                                                   float* __restrict__ proj,
                                                   float* __restrict__ projT,
                                                   u16* __restrict__ Lbf) {
    __shared__ float hs_s[64][68];
    __shared__ float w_s[64][68];
    const int tid = threadIdx.x;
    const int tx = tid & 15, ty = tid >> 4;
    const int m0 = blockIdx.x * 64, n0 = blockIdx.y * 64;
    float acc[4][4] = {};
    for (int k0 = 0; k0 < CIN; k0 += 64) {
        __syncthreads();
#pragma unroll
        for (int rep = 0; rep < 4; ++rep) {
            int lin = rep * 1024 + tid * 4;
            int rl = lin >> 6, kl = lin & 63;
            float4 hv = *(const float4*)&hs[(n0 + rl) * CIN + k0 + kl];
            hs_s[kl + 0][rl] = hv.x; hs_s[kl + 1][rl] = hv.y;
            hs_s[kl + 2][rl] = hv.z; hs_s[kl + 3][rl] = hv.w;
            float4 wv = *(const float4*)&W[(m0 + rl) * CIN + k0 + kl];
            w_s[kl + 0][rl] = wv.x; w_s[kl + 1][rl] = wv.y;
            w_s[kl + 2][rl] = wv.z; w_s[kl + 3][rl] = wv.w;
        }
        __syncthreads();
#pragma unroll 16
        for (int kk = 0; kk < 64; ++kk) {
            float4 a4 = *(const float4*)&hs_s[kk][ty * 4];
            float4 b4 = *(const float4*)&w_s[kk][tx * 4];
            float av[4] = {a4.x, a4.y, a4.z, a4.w};
            float bv[4] = {b4.x, b4.y, b4.z, b4.w};
#pragma unroll
            for (int a_ = 0; a_ < 4; ++a_) {
#pragma unroll
                for (int b_ = 0; b_ < 4; ++b_) {
                    acc[a_][b_] = fmaf(av[a_], bv[b_], acc[a_][b_]);
                }
            }
        }
    }
#pragma unroll
    for (int a_ = 0; a_ < 4; ++a_) {
        int n = n0 + ty * 4 + a_;
#pragma unroll
        for (int b_ = 0; b_ < 4; ++b_) {
            int m = m0 + tx * 4 + b_;
            int s = m >> 8, hh = (m >> 5) & 7, d = m & 31;
            proj[s * (H * N * D) + hh * (N * D) + n * D + d] = acc[a_][b_];
            if (s >= 3) projT[(s - 3) * (H * D * N) + hh * (D * N) + d * N + n] = acc[a_][b_];
            else        Lbf[((s * H + hh) * N + n) * D + d] = f2bf(acc[a_][b_]);
        }
    }
}

// ---------------- K2: scores via MFMA bf16 + fused max atomics ----------------
// t=0: XT[k,j] = c.b (row-max key) ; t=1: Y[k,i] = c.a (COLUMN-max key) ;
// t=2: Z[i,j] = a.b (row-max key).  K = 32 = one MFMA.
// block: 128r x 128c tile, 4 waves; wave w owns rows [r0+w*32,+32) (fi=2) x 128 cols (fk=8)
__global__ __launch_bounds__(256) void scores_mfma(const u16* __restrict__ Lbf,
                                                   float* __restrict__ S,
                                                   u32* __restrict__ keys) {
    const int tid = threadIdx.x;
    const int w = tid >> 6, lane = tid & 63;
    const int l15 = lane & 15, lhi = lane >> 4;
    const int r0 = (blockIdx.x % 3) * 128, c0 = (blockIdx.x / 3) * 128;
    const int h = blockIdx.y;
    const int t = blockIdx.z;
    const int Lidx = (t == 2) ? 0 : 2;
    const int Ridx = (t == 1) ? 0 : 1;
    const u16* Lp = Lbf + ((Lidx * H + h) * N) * D;
    const u16* Rp = Lbf + ((Ridx * H + h) * N) * D;
    float* Sp = S + t * HNN + h * (N * N);
    u32* krow = keys + t * (H * N) + h * N;   // t=0: row keys, t=1: column keys, t=2: row keys

    short8 a[2], b[8];
#pragma unroll
    for (int fi = 0; fi < 2; ++fi)
        a[fi] = *(const short8*)&Lp[(r0 + w * 32 + fi * 16 + l15) * D + lhi * 8];
#pragma unroll
    for (int fk = 0; fk < 8; ++fk)
        b[fk] = *(const short8*)&Rp[(c0 + fk * 16 + l15) * D + lhi * 8];

    f32x4 acc[2][8];
#pragma unroll
    for (int fi = 0; fi < 2; ++fi)
#pragma unroll
        for (int fk = 0; fk < 8; ++fk) {
            acc[fi][fk] = (f32x4){0.f, 0.f, 0.f, 0.f};
            acc[fi][fk] = __builtin_amdgcn_mfma_f32_16x16x32_bf16(a[fi], b[fk], acc[fi][fk], 0, 0, 0);
        }

    if (t == 1) {
        // column max: in-lane over fi/reg, then across lhi groups (rows)
#pragma unroll
        for (int fk = 0; fk < 8; ++fk) {
            float cm = -3.0e38f;
#pragma unroll
            for (int fi = 0; fi < 2; ++fi)
#pragma unroll
                for (int reg = 0; reg < 4; ++reg)
                    cm = fmaxf(cm, acc[fi][fk][reg] * SCALER);
            cm = fmaxf(cm, __shfl_xor(cm, 16));
            cm = fmaxf(cm, __shfl_xor(cm, 32));
            if (lhi == 0) atomicMax(&krow[c0 + fk * 16 + l15], fkey(cm));
        }
#pragma unroll
        for (int fi = 0; fi < 2; ++fi)
#pragma unroll
            for (int reg = 0; reg < 4; ++reg) {
                const int row = r0 + w * 32 + fi * 16 + lhi * 4 + reg;
#pragma unroll
                for (int fk = 0; fk < 8; ++fk)
                    Sp[row * N + c0 + fk * 16 + l15] = acc[fi][fk][reg] * SCALER;
            }
    } else {
#pragma unroll
        for (int fi = 0; fi < 2; ++fi) {
#pragma unroll
            for (int reg = 0; reg < 4; ++reg) {
                const int row = r0 + w * 32 + fi * 16 + lhi * 4 + reg;
                float rm = -3.0e38f;
#pragma unroll
                for (int fk = 0; fk < 8; ++fk) {
                    float v = acc[fi][fk][reg] * SCALER;
                    Sp[row * N + c0 + fk * 16 + l15] = v;
                    rm = fmaxf(rm, v);
                }
                rm = fmaxf(rm, __shfl_xor(rm, 1));
                rm = fmaxf(rm, __shfl_xor(rm, 2));
                rm = fmaxf(rm, __shfl_xor(rm, 4));
                rm = fmaxf(rm, __shfl_xor(rm, 8));
                if (l15 == 0) atomicMax(&krow[row], fkey(rm));
            }
        }
    }
}

// ---------------- K3: exp (reduce_mx folded in) ----------------
// t=0: m = global max of plane (block re-reduces 384 row keys); packed bf16 out
// t=1: m = per-COLUMN key; fp32 in place (Y[k][i])
// t=2: m = per-row key; row bf16 out
// Xpack layout: [h][kt=k/16][jt=j/32][lane][8], lane = (k&15) | ((j>>3)&3)<<4
__global__ void exp_kernel(float* __restrict__ S, const u32* __restrict__ keys,
                           u16* __restrict__ Xbf, u16* __restrict__ Zbf) {
    int f8 = blockIdx.x * 256 + threadIdx.x;  // 442368 total
    int flat = f8 * 8;
    int t = flat / HNN;         // uniform per block (HNN % 2048 == 0)
    int rem = flat - t * HNN;
    int h = rem / (N * N);      // uniform per block
    int rc = rem - h * (N * N);
    int r = rc / N;
    int c = rc - r * N;
    float4 v0 = *(float4*)&S[flat];
    float4 v1 = *(float4*)&S[flat + 4];
    float e[8];
    if (t == 1) {
        // per-column keys (8 consecutive columns)
        float vv[8] = {v0.x, v0.y, v0.z, v0.w, v1.x, v1.y, v1.z, v1.w};
        const u32* kc = keys + (H * N) + h * N + c;
#pragma unroll
        for (int q = 0; q < 8; ++q) e[q] = __expf(vv[q] - fkey_dec(kc[q]));
        float4 o0 = {e[0], e[1], e[2], e[3]}, o1 = {e[4], e[5], e[6], e[7]};
        *(float4*)&S[flat] = o0;
        *(float4*)&S[flat + 4] = o1;
    } else {
        float m;
        if (t == 0) {
            __shared__ u32 kr[4];
            u32 km = 0;
            for (int q = threadIdx.x; q < N; q += 256) km = max(km, keys[h * N + q]);
#pragma unroll
            for (int off = 32; off; off >>= 1) km = max(km, (u32)__shfl_down(km, off));
            if ((threadIdx.x & 63) == 0) kr[threadIdx.x >> 6] = km;
            __syncthreads();
            m = fkey_dec(max(max(kr[0], kr[1]), max(kr[2], kr[3])));
        } else {
            m = fkey_dec(keys[2 * (H * N) + h * N + r]);
        }
        e[0] = __expf(v0.x - m); e[1] = __expf(v0.y - m);
        e[2] = __expf(v0.z - m); e[3] = __expf(v0.w - m);
        e[4] = __expf(v1.x - m); e[5] = __expf(v1.y - m);
        e[6] = __expf(v1.z - m); e[7] = __expf(v1.w - m);
        short8 ov;
#pragma unroll
        for (int q = 0; q < 8; ++q) ov[q] = (short)f2bf(e[q]);
        if (t == 0) {
            const int kt = r >> 4, jt = c >> 5;
            const int lanep = (r & 15) | (((c >> 3) & 3) << 4);
            u16* dst = Xbf + (((h * 24 + kt) * 12 + jt) << 9) + lanep * 8;
            *(short8*)dst = ov;
        } else {
            u16* dst = Zbf + h * (N * N) + rc;
            *(short8*)dst = ov;
        }
    }
}

// ---------------- K4: cubic contraction via MFMA bf16, v17 (Y-coalesced epilogue) ----------------
// block = (h, i-tile of 32, d-group of 2). 384 thr = 6 waves; wave w owns k in [w*64,+64).
// Epilogue now reads Y[k][i] with contiguous float4 loads shared by d0/d1.
__global__ __launch_bounds__(384, 4) void cubic_mfma(
        const u16* __restrict__ Xbf, const u16* __restrict__ Zbf,
        const float* __restrict__ Y, const float* __restrict__ vjT,
        const float* __restrict__ vkT, float* __restrict__ NumB,
        float* __restrict__ DenB) {
    const int orig = blockIdx.x;             // 0..1631 (1632 = 8 x 204, bijective)
    const int wg = (orig & 7) * 204 + (orig >> 3);
    const int h   = wg / 204;                // one head per XCD
    const int rem = wg - h * 204;
    const int dg  = rem / 12;                // 0..16
    const int it12 = rem - dg * 12;          // 0..11
    const int i0  = it12 * 32;
    const bool dgden = (dg == 16);
    const int d0 = dgden ? 0 : 2 * dg;
    const int d1 = dgden ? 0 : 2 * dg + 1;
    const int tid = threadIdx.x;
    const int w = tid >> 6, lane = tid & 63;
    __shared__ u16 A_lds[2 * 32 * N];        // [t][f(24)][64][8] frag-packed (48 KB)
    __shared__ float red[2][6][32];
    u16* A0 = A_lds;
    u16* A1 = A_lds + 32 * N;
    const u16* Zh = Zbf + h * (N * N);
    const float* Yh = Y + h * (N * N);       // Y[k][i]
    const float* vjd0 = vjT + h * (D * N) + d0 * N;
    const float* vjd1 = vjT + h * (D * N) + d1 * N;
    const float* vkd0 = vkT + h * (D * N) + d0 * N;
    const float* vkd1 = vkT + h * (D * N) + d1 * N;

    // ---- A-prep: coalesced global reads, frag-packed LDS writes (both tiles)
    {
#pragma unroll
        for (int it = 0; it < 4; ++it) {
            const int g = it * 384 + tid;        // 0..1535
            const int row = g / 48;              // 0..31
            const int cb = g - row * 48;
            const int jb = cb * 8;
            const int fi = row >> 4, l15r = row & 15;
            const int js = cb >> 2, sub = cb & 3;
            const int f = fi * 12 + js;          // 0..23
            const int dst = f * 512 + (((l15r | (sub << 4)) ^ (f & 7)) << 3);
            short8 zv = *(const short8*)&Zh[(i0 + row) * N + jb];
            if (dgden) {
                *(short8*)&A0[dst] = zv;
                *(short8*)&A1[dst] = zv;
            } else {
                float4 p0 = *(const float4*)&vjd0[jb];
                float4 p1 = *(const float4*)&vjd0[jb + 4];
                float4 q0 = *(const float4*)&vjd1[jb];
                float4 q1 = *(const float4*)&vjd1[jb + 4];
                float v0[8] = {p0.x, p0.y, p0.z, p0.w, p1.x, p1.y, p1.z, p1.w};
                float v1[8] = {q0.x, q0.y, q0.z, q0.w, q1.x, q1.y, q1.z, q1.w};
                short8 o0, o1;
#pragma unroll
                for (int e = 0; e < 8; ++e) {
                    float zf = bf2f((u16)zv[e]);
                    o0[e] = (short)f2bf(zf * v0[e]);
                    o1[e] = (short)f2bf(zf * v1[e]);
                }
                *(short8*)&A0[dst] = o0;
                *(short8*)&A1[dst] = o1;
            }
        }
    }
    __syncthreads();

    // ---- MFMA main loop: no barriers, k held in accumulators
    f32x4 acc0[2][4], acc1[2][4];
#pragma unroll
    for (int fi = 0; fi < 2; ++fi)
#pragma unroll
        for (int fk = 0; fk < 4; ++fk) {
            acc0[fi][fk] = (f32x4){0.f, 0.f, 0.f, 0.f};
            acc1[fi][fk] = (f32x4){0.f, 0.f, 0.f, 0.f};
        }

    const int l15 = lane & 15;
    const u16* Bp = Xbf + ((h * 24 + w * 4) * 12 << 9) + lane * 8;
    const int KTS = 12 * 512;         // k-tile stride (u16)

#pragma unroll
    for (int js = 0; js < 12; ++js) {
        short8 a0[2], a1[2];
#pragma unroll
        for (int fi = 0; fi < 2; ++fi) {
            const int f = fi * 12 + js;
            const int off = f * 512 + ((lane ^ (f & 7)) << 3);
            a0[fi] = *(const short8*)&A0[off];
            a1[fi] = *(const short8*)&A1[off];
        }
        short8 b[4];
#pragma unroll
        for (int fk = 0; fk < 4; ++fk)
            b[fk] = *(const short8*)&Bp[fk * KTS + js * 512];
        __builtin_amdgcn_s_setprio(1);
#pragma unroll
        for (int fk = 0; fk < 4; ++fk) {
#pragma unroll
            for (int fi = 0; fi < 2; ++fi) {
                acc0[fi][fk] = __builtin_amdgcn_mfma_f32_16x16x32_bf16(a0[fi], b[fk], acc0[fi][fk], 0, 0, 0);
                acc1[fi][fk] = __builtin_amdgcn_mfma_f32_16x16x32_bf16(a1[fi], b[fk], acc1[fi][fk], 0, 0, 0);
            }
        }
        __builtin_amdgcn_s_setprio(0);
    }

    // ---- epilogue (merged d0/d1): Y[k][i] contiguous float4 loads, weight, k-reduce
    const int rbase = (lane >> 4) << 2;
    float np0[2][4], np1[2][4];
#pragma unroll
    for (int fi = 0; fi < 2; ++fi)
#pragma unroll
        for (int reg = 0; reg < 4; ++reg) { np0[fi][reg] = 0.f; np1[fi][reg] = 0.f; }
#pragma unroll
    for (int fk = 0; fk < 4; ++fk) {
        const int kcol = w * 64 + fk * 16 + l15;
        const float vk0 = dgden ? 1.0f : vkd0[kcol];
        const float vk1 = dgden ? 1.0f : vkd1[kcol];
#pragma unroll
        for (int fi = 0; fi < 2; ++fi) {
            const float4 yv = *(const float4*)&Yh[kcol * N + i0 + fi * 16 + rbase];
            const float yarr[4] = {yv.x, yv.y, yv.z, yv.w};
#pragma unroll
            for (int reg = 0; reg < 4; ++reg) {
                np0[fi][reg] = fmaf(acc0[fi][fk][reg], yarr[reg] * vk0, np0[fi][reg]);
                np1[fi][reg] = fmaf(acc1[fi][fk][reg], yarr[reg] * vk1, np1[fi][reg]);
            }
        }
    }
#pragma unroll
    for (int fi = 0; fi < 2; ++fi) {
#pragma unroll
        for (int reg = 0; reg < 4; ++reg) {
            float v0 = np0[fi][reg];
            v0 += __shfl_xor(v0, 1); v0 += __shfl_xor(v0, 2);
            v0 += __shfl_xor(v0, 4); v0 += __shfl_xor(v0, 8);
            np0[fi][reg] = v0;
            float v1 = np1[fi][reg];
            v1 += __shfl_xor(v1, 1); v1 += __shfl_xor(v1, 2);
            v1 += __shfl_xor(v1, 4); v1 += __shfl_xor(v1, 8);
            np1[fi][reg] = v1;
        }
    }
    if (l15 == 0) {
#pragma unroll
        for (int fi = 0; fi < 2; ++fi)
#pragma unroll
            for (int reg = 0; reg < 4; ++reg) {
                red[0][w][fi * 16 + rbase + reg] = np0[fi][reg];
                red[1][w][fi * 16 + rbase + reg] = np1[fi][reg];
            }
    }
    __syncthreads();
    if (tid < 32) {
        float s = 0.f;
#pragma unroll
        for (int ww = 0; ww < 6; ++ww) s += red[0][ww][tid];
        if (!dgden) NumB[h * (N * D) + (i0 + tid) * D + 2 * dg] = s;
        else        DenB[h * N + i0 + tid] = s;
    } else if (tid < 64 && !dgden) {
        const int i = tid - 32;
        float s = 0.f;
#pragma unroll
        for (int ww = 0; ww < 6; ++ww) s += red[1][ww][i];
        NumB[h * (N * D) + (i0 + i) * D + 2 * dg + 1] = s;
    }
}

// ---------------- K5: normalize + fp32 output [n, h*D+d] ----------------
__global__ void out_kernel(const float* __restrict__ NumB, const float* __restrict__ DenB,
                           float* __restrict__ out) {
    int idx = blockIdx.x * 256 + threadIdx.x;  // 0..98303
    int n = idx >> 8;
    int ch = idx & 255;
    int hh = ch >> 5, d = ch & 31;
    float v = NumB[hh * (N * D) + n * D + d] / (DenB[hh * N + n] + EPS);
    out[idx] = v;
}

extern "C" void kernel_launch(void* const* d_in, const int* in_sizes, int n_in,
                              void* d_out, int out_size, void* d_ws, size_t ws_size,
                              hipStream_t stream) {
    const float* hs = (const float*)d_in[0];
    const float* W  = (const float*)d_in[1];
    float* ws = (float*)d_ws;
    float* proj  = ws + PROJ_OFF;
    float* S     = ws + S_OFF;
    float* projT = ws + VJT_OFF;    // vj rows, then vk rows at +H*D*N
    float* NumB  = ws + NUM_OFF;
    float* DenB  = ws + DEN_OFF;
    u16*   Xbf   = (u16*)(ws + XBF_OFF);
    u16*   Zbf   = (u16*)(ws + ZBF_OFF);
    u32*   keys  = (u32*)(ws + KEYS_OFF);   // 3*H*N keys
    u16*   Lbf   = (u16*)(ws + LBF_OFF);    // bf16 a,b,c
    float* out = (float*)d_out;

    hipMemsetAsync(keys, 0, 3 * H * N * sizeof(u32), stream);
    proj_kernel<<<dim3(20, 6), 256, 0, stream>>>(hs, W, proj, projT, Lbf);
    scores_mfma<<<dim3(9, 8, 3), 256, 0, stream>>>(Lbf, S, keys);
    exp_kernel<<<1728, 256, 0, stream>>>(S, keys, Xbf, Zbf);
    cubic_mfma<<<dim3(1632), 384, 0, stream>>>(Xbf, Zbf, S + HNN, ws + VJT_OFF,
                                               ws + VKT_OFF, NumB, DenB);
    out_kernel<<<(H * N * D) / 256, 256, 0, stream>>>(NumB, DenB, out);
}

// Round 20
// 76.247 us; speedup vs baseline: 1.2308x; 1.2308x over previous
//
#include <hip/hip_runtime.h>
#include <hip/hip_bf16.h>

typedef unsigned short u16;
typedef unsigned int u32;
typedef __attribute__((ext_vector_type(8))) short short8;
typedef __attribute__((ext_vector_type(4))) float f32x4;

#define H 8
#define N 384
#define D 32
#define CIN 256
#define HNN (H * N * N)
#define SCALER 0.17677669529663687f
#define EPS 1e-9f
#define SHIFT 5.0f   // constant stabilization shift; cancels exactly in Num/Den ratio

// workspace float offsets
#define S_OFF    491520u         // only plane 1 used: Y[k][i] = exp(y-SHIFT), fp32
#define VJT_OFF  4030464u        // H*D*N: vj transposed [h][d][n]
#define VKT_OFF  4128768u        // H*D*N
#define NUM_OFF  4233224u        // H*N*D
#define DEN_OFF  4331528u        // H*N
#define XBF_OFF  4334600u        // ushort[H*N*N]: exp(X)-packed in MFMA-frag order
#define ZBF_OFF  4924424u        // ushort[H*N*N]: exp(Z) bf16 row-major
#define LBF_OFF  5523464u        // u16[3*H*N*D]: bf16 a,b,c for scores MFMA

__device__ inline float bf2f(u16 u) {
    union { unsigned int x; float f; } c; c.x = ((unsigned int)u) << 16; return c.f;
}
__device__ inline u16 f2bf(float f) {
    unsigned int x = __float_as_uint(f);
    return (u16)((x + 0x7FFFu + ((x >> 16) & 1u)) >> 16);
}

// ---------------- K1: projection GEMM  wx[n,m] = sum_k hs[n,k]*W[m,k] ----------------
// outputs: Lbf bf16 (a,b,c) and projT fp32 (vj,vk transposed). fp32 proj was dead code.
__global__ __launch_bounds__(256) void proj_kernel(const float* __restrict__ hs,
                                                   const float* __restrict__ W,
                                                   float* __restrict__ projT,
                                                   u16* __restrict__ Lbf) {
    __shared__ float hs_s[64][68];
    __shared__ float w_s[64][68];
    const int tid = threadIdx.x;
    const int tx = tid & 15, ty = tid >> 4;
    const int m0 = blockIdx.x * 64, n0 = blockIdx.y * 64;
    float acc[4][4] = {};
    for (int k0 = 0; k0 < CIN; k0 += 64) {
        __syncthreads();
#pragma unroll
        for (int rep = 0; rep < 4; ++rep) {
            int lin = rep * 1024 + tid * 4;
            int rl = lin >> 6, kl = lin & 63;
            float4 hv = *(const float4*)&hs[(n0 + rl) * CIN + k0 + kl];
            hs_s[kl + 0][rl] = hv.x; hs_s[kl + 1][rl] = hv.y;
            hs_s[kl + 2][rl] = hv.z; hs_s[kl + 3][rl] = hv.w;
            float4 wv = *(const float4*)&W[(m0 + rl) * CIN + k0 + kl];
            w_s[kl + 0][rl] = wv.x; w_s[kl + 1][rl] = wv.y;
            w_s[kl + 2][rl] = wv.z; w_s[kl + 3][rl] = wv.w;
        }
        __syncthreads();
#pragma unroll 16
        for (int kk = 0; kk < 64; ++kk) {
            float4 a4 = *(const float4*)&hs_s[kk][ty * 4];
            float4 b4 = *(const float4*)&w_s[kk][tx * 4];
            float av[4] = {a4.x, a4.y, a4.z, a4.w};
            float bv[4] = {b4.x, b4.y, b4.z, b4.w};
#pragma unroll
            for (int a_ = 0; a_ < 4; ++a_) {
#pragma unroll
                for (int b_ = 0; b_ < 4; ++b_) {
                    acc[a_][b_] = fmaf(av[a_], bv[b_], acc[a_][b_]);
                }
            }
        }
    }
#pragma unroll
    for (int a_ = 0; a_ < 4; ++a_) {
        int n = n0 + ty * 4 + a_;
#pragma unroll
        for (int b_ = 0; b_ < 4; ++b_) {
            int m = m0 + tx * 4 + b_;
            int s = m >> 8, hh = (m >> 5) & 7, d = m & 31;
            if (s >= 3) projT[(s - 3) * (H * D * N) + hh * (D * N) + d * N + n] = acc[a_][b_];
            else        Lbf[((s * H + hh) * N + n) * D + d] = f2bf(acc[a_][b_]);
        }
    }
}

// ---------------- K2: scores via MFMA bf16 + FUSED exp(S - SHIFT) ----------------
// t=0: XT[k,j] = c.b -> packed bf16 Xbf ; t=1: Y[k,i] = c.a -> fp32 Y plane ;
// t=2: Z[i,j] = a.b -> row bf16 Zbf.  K = 32 = one MFMA.
// block: 128r x 128c tile, 4 waves; wave w owns rows [r0+w*32,+32) (fi=2) x 128 cols (fk=8)
__global__ __launch_bounds__(256) void scores_mfma(const u16* __restrict__ Lbf,
                                                   float* __restrict__ Y,
                                                   u16* __restrict__ Xbf,
                                                   u16* __restrict__ Zbf) {
    const int tid = threadIdx.x;
    const int w = tid >> 6, lane = tid & 63;
    const int l15 = lane & 15, lhi = lane >> 4;
    const int r0 = (blockIdx.x % 3) * 128, c0 = (blockIdx.x / 3) * 128;
    const int h = blockIdx.y;
    const int t = blockIdx.z;
    const int Lidx = (t == 2) ? 0 : 2;
    const int Ridx = (t == 1) ? 0 : 1;
    const u16* Lp = Lbf + ((Lidx * H + h) * N) * D;
    const u16* Rp = Lbf + ((Ridx * H + h) * N) * D;

    short8 a[2], b[8];
#pragma unroll
    for (int fi = 0; fi < 2; ++fi)
        a[fi] = *(const short8*)&Lp[(r0 + w * 32 + fi * 16 + l15) * D + lhi * 8];
#pragma unroll
    for (int fk = 0; fk < 8; ++fk)
        b[fk] = *(const short8*)&Rp[(c0 + fk * 16 + l15) * D + lhi * 8];

    f32x4 acc[2][8];
#pragma unroll
    for (int fi = 0; fi < 2; ++fi)
#pragma unroll
        for (int fk = 0; fk < 8; ++fk) {
            acc[fi][fk] = (f32x4){0.f, 0.f, 0.f, 0.f};
            acc[fi][fk] = __builtin_amdgcn_mfma_f32_16x16x32_bf16(a[fi], b[fk], acc[fi][fk], 0, 0, 0);
        }

    if (t == 1) {
        float* Yp = Y + h * (N * N);
#pragma unroll
        for (int fi = 0; fi < 2; ++fi)
#pragma unroll
            for (int reg = 0; reg < 4; ++reg) {
                const int row = r0 + w * 32 + fi * 16 + lhi * 4 + reg;
#pragma unroll
                for (int fk = 0; fk < 8; ++fk)
                    Yp[row * N + c0 + fk * 16 + l15] =
                        __expf(fmaf(acc[fi][fk][reg], SCALER, -SHIFT));
            }
    } else if (t == 0) {
        // packed layout: [h][kt=k/16][jt=j/32][lanep][j&7], lanep=(k&15)|((j>>3)&3)<<4
#pragma unroll
        for (int fi = 0; fi < 2; ++fi)
#pragma unroll
            for (int reg = 0; reg < 4; ++reg) {
                const int row = r0 + w * 32 + fi * 16 + lhi * 4 + reg;   // k
                const int kt = row >> 4;
                const int lp_row = row & 15;
#pragma unroll
                for (int fk = 0; fk < 8; ++fk) {
                    const int col = c0 + fk * 16 + l15;                  // j
                    const float e = __expf(fmaf(acc[fi][fk][reg], SCALER, -SHIFT));
                    const int jt = col >> 5;
                    const int lanep = lp_row | (((col >> 3) & 3) << 4);
                    Xbf[(((h * 24 + kt) * 12 + jt) << 9) + lanep * 8 + (col & 7)] = f2bf(e);
                }
            }
    } else {
        u16* Zp = Zbf + h * (N * N);
#pragma unroll
        for (int fi = 0; fi < 2; ++fi)
#pragma unroll
            for (int reg = 0; reg < 4; ++reg) {
                const int row = r0 + w * 32 + fi * 16 + lhi * 4 + reg;
#pragma unroll
                for (int fk = 0; fk < 8; ++fk) {
                    const float e = __expf(fmaf(acc[fi][fk][reg], SCALER, -SHIFT));
                    Zp[row * N + c0 + fk * 16 + l15] = f2bf(e);
                }
            }
    }
}

// ---------------- K3: cubic contraction via MFMA bf16 (unchanged from r19) ----------------
__global__ __launch_bounds__(384, 4) void cubic_mfma(
        const u16* __restrict__ Xbf, const u16* __restrict__ Zbf,
        const float* __restrict__ Y, const float* __restrict__ vjT,
        const float* __restrict__ vkT, float* __restrict__ NumB,
        float* __restrict__ DenB) {
    const int orig = blockIdx.x;             // 0..1631 (1632 = 8 x 204, bijective)
    const int wg = (orig & 7) * 204 + (orig >> 3);
    const int h   = wg / 204;                // one head per XCD
    const int rem = wg - h * 204;
    const int dg  = rem / 12;                // 0..16
    const int it12 = rem - dg * 12;          // 0..11
    const int i0  = it12 * 32;
    const bool dgden = (dg == 16);
    const int d0 = dgden ? 0 : 2 * dg;
    const int d1 = dgden ? 0 : 2 * dg + 1;
    const int tid = threadIdx.x;
    const int w = tid >> 6, lane = tid & 63;
    __shared__ u16 A_lds[2 * 32 * N];        // [t][f(24)][64][8] frag-packed (48 KB)
    __shared__ float red[2][6][32];
    u16* A0 = A_lds;
    u16* A1 = A_lds + 32 * N;
    const u16* Zh = Zbf + h * (N * N);
    const float* Yh = Y + h * (N * N);       // Y[k][i]
    const float* vjd0 = vjT + h * (D * N) + d0 * N;
    const float* vjd1 = vjT + h * (D * N) + d1 * N;
    const float* vkd0 = vkT + h * (D * N) + d0 * N;
    const float* vkd1 = vkT + h * (D * N) + d1 * N;

    // ---- A-prep: coalesced global reads, frag-packed LDS writes (both tiles)
    {
#pragma unroll
        for (int it = 0; it < 4; ++it) {
            const int g = it * 384 + tid;        // 0..1535
            const int row = g / 48;              // 0..31
            const int cb = g - row * 48;
            const int jb = cb * 8;
            const int fi = row >> 4, l15r = row & 15;
            const int js = cb >> 2, sub = cb & 3;
            const int f = fi * 12 + js;          // 0..23
            const int dst = f * 512 + (((l15r | (sub << 4)) ^ (f & 7)) << 3);
            short8 zv = *(const short8*)&Zh[(i0 + row) * N + jb];
            if (dgden) {
                *(short8*)&A0[dst] = zv;
                *(short8*)&A1[dst] = zv;
            } else {
                float4 p0 = *(const float4*)&vjd0[jb];
                float4 p1 = *(const float4*)&vjd0[jb + 4];
                float4 q0 = *(const float4*)&vjd1[jb];
                float4 q1 = *(const float4*)&vjd1[jb + 4];
                float v0[8] = {p0.x, p0.y, p0.z, p0.w, p1.x, p1.y, p1.z, p1.w};
                float v1[8] = {q0.x, q0.y, q0.z, q0.w, q1.x, q1.y, q1.z, q1.w};
                short8 o0, o1;
#pragma unroll
                for (int e = 0; e < 8; ++e) {
                    float zf = bf2f((u16)zv[e]);
                    o0[e] = (short)f2bf(zf * v0[e]);
                    o1[e] = (short)f2bf(zf * v1[e]);
                }
                *(short8*)&A0[dst] = o0;
                *(short8*)&A1[dst] = o1;
            }
        }
    }
    __syncthreads();

    // ---- MFMA main loop: no barriers, k held in accumulators
    f32x4 acc0[2][4], acc1[2][4];
#pragma unroll
    for (int fi = 0; fi < 2; ++fi)
#pragma unroll
        for (int fk = 0; fk < 4; ++fk) {
            acc0[fi][fk] = (f32x4){0.f, 0.f, 0.f, 0.f};
            acc1[fi][fk] = (f32x4){0.f, 0.f, 0.f, 0.f};
        }

    const int l15 = lane & 15;
    const u16* Bp = Xbf + ((h * 24 + w * 4) * 12 << 9) + lane * 8;
    const int KTS = 12 * 512;         // k-tile stride (u16)

#pragma unroll
    for (int js = 0; js < 12; ++js) {
        short8 a0[2], a1[2];
#pragma unroll
        for (int fi = 0; fi < 2; ++fi) {
            const int f = fi * 12 + js;
            const int off = f * 512 + ((lane ^ (f & 7)) << 3);
            a0[fi] = *(const short8*)&A0[off];
            a1[fi] = *(const short8*)&A1[off];
        }
        short8 b[4];
#pragma unroll
        for (int fk = 0; fk < 4; ++fk)
            b[fk] = *(const short8*)&Bp[fk * KTS + js * 512];
        __builtin_amdgcn_s_setprio(1);
#pragma unroll
        for (int fk = 0; fk < 4; ++fk) {
#pragma unroll
            for (int fi = 0; fi < 2; ++fi) {
                acc0[fi][fk] = __builtin_amdgcn_mfma_f32_16x16x32_bf16(a0[fi], b[fk], acc0[fi][fk], 0, 0, 0);
                acc1[fi][fk] = __builtin_amdgcn_mfma_f32_16x16x32_bf16(a1[fi], b[fk], acc1[fi][fk], 0, 0, 0);
            }
        }
        __builtin_amdgcn_s_setprio(0);
    }

    // ---- epilogue (merged d0/d1): Y[k][i] contiguous float4 loads, weight, k-reduce
    const int rbase = (lane >> 4) << 2;
    float np0[2][4], np1[2][4];
#pragma unroll
    for (int fi = 0; fi < 2; ++fi)
#pragma unroll
        for (int reg = 0; reg < 4; ++reg) { np0[fi][reg] = 0.f; np1[fi][reg] = 0.f; }
#pragma unroll
    for (int fk = 0; fk < 4; ++fk) {
        const int kcol = w * 64 + fk * 16 + l15;
        const float vk0 = dgden ? 1.0f : vkd0[kcol];
        const float vk1 = dgden ? 1.0f : vkd1[kcol];
#pragma unroll
        for (int fi = 0; fi < 2; ++fi) {
            const float4 yv = *(const float4*)&Yh[kcol * N + i0 + fi * 16 + rbase];
            const float yarr[4] = {yv.x, yv.y, yv.z, yv.w};
#pragma unroll
            for (int reg = 0; reg < 4; ++reg) {
                np0[fi][reg] = fmaf(acc0[fi][fk][reg], yarr[reg] * vk0, np0[fi][reg]);
                np1[fi][reg] = fmaf(acc1[fi][fk][reg], yarr[reg] * vk1, np1[fi][reg]);
            }
        }
    }
#pragma unroll
    for (int fi = 0; fi < 2; ++fi) {
#pragma unroll
        for (int reg = 0; reg < 4; ++reg) {
            float v0 = np0[fi][reg];
            v0 += __shfl_xor(v0, 1); v0 += __shfl_xor(v0, 2);
            v0 += __shfl_xor(v0, 4); v0 += __shfl_xor(v0, 8);
            np0[fi][reg] = v0;
            float v1 = np1[fi][reg];
            v1 += __shfl_xor(v1, 1); v1 += __shfl_xor(v1, 2);
            v1 += __shfl_xor(v1, 4); v1 += __shfl_xor(v1, 8);
            np1[fi][reg] = v1;
        }
    }
    if (l15 == 0) {
#pragma unroll
        for (int fi = 0; fi < 2; ++fi)
#pragma unroll
            for (int reg = 0; reg < 4; ++reg) {
                red[0][w][fi * 16 + rbase + reg] = np0[fi][reg];
                red[1][w][fi * 16 + rbase + reg] = np1[fi][reg];
            }
    }
    __syncthreads();
    if (tid < 32) {
        float s = 0.f;
#pragma unroll
        for (int ww = 0; ww < 6; ++ww) s += red[0][ww][tid];
        if (!dgden) NumB[h * (N * D) + (i0 + tid) * D + 2 * dg] = s;
        else        DenB[h * N + i0 + tid] = s;
    } else if (tid < 64 && !dgden) {
        const int i = tid - 32;
        float s = 0.f;
#pragma unroll
        for (int ww = 0; ww < 6; ++ww) s += red[1][ww][i];
        NumB[h * (N * D) + (i0 + i) * D + 2 * dg + 1] = s;
    }
}

// ---------------- K4: normalize + fp32 output [n, h*D+d] ----------------
__global__ void out_kernel(const float* __restrict__ NumB, const float* __restrict__ DenB,
                           float* __restrict__ out) {
    int idx = blockIdx.x * 256 + threadIdx.x;  // 0..98303
    int n = idx >> 8;
    int ch = idx & 255;
    int hh = ch >> 5, d = ch & 31;
    float v = NumB[hh * (N * D) + n * D + d] / (DenB[hh * N + n] + EPS);
    out[idx] = v;
}

extern "C" void kernel_launch(void* const* d_in, const int* in_sizes, int n_in,
                              void* d_out, int out_size, void* d_ws, size_t ws_size,
                              hipStream_t stream) {
    const float* hs = (const float*)d_in[0];
    const float* W  = (const float*)d_in[1];
    float* ws = (float*)d_ws;
    float* Yp    = ws + S_OFF + HNN;   // plane 1 of the old S buffer: Y[k][i]
    float* projT = ws + VJT_OFF;       // vj rows, then vk rows at +H*D*N
    float* NumB  = ws + NUM_OFF;
    float* DenB  = ws + DEN_OFF;
    u16*   Xbf   = (u16*)(ws + XBF_OFF);
    u16*   Zbf   = (u16*)(ws + ZBF_OFF);
    u16*   Lbf   = (u16*)(ws + LBF_OFF);
    float* out = (float*)d_out;

    proj_kernel<<<dim3(20, 6), 256, 0, stream>>>(hs, W, projT, Lbf);
    scores_mfma<<<dim3(9, 8, 3), 256, 0, stream>>>(Lbf, Yp, Xbf, Zbf);
    cubic_mfma<<<dim3(1632), 384, 0, stream>>>(Xbf, Zbf, Yp, ws + VJT_OFF,
                                               ws + VKT_OFF, NumB, DenB);
    out_kernel<<<(H * N * D) / 256, 256, 0, stream>>>(NumB, DenB, out);
}

// Round 21
// 75.666 us; speedup vs baseline: 1.2403x; 1.0077x over previous
//
#include <hip/hip_runtime.h>
#include <hip/hip_bf16.h>

typedef unsigned short u16;
typedef unsigned int u32;
typedef __attribute__((ext_vector_type(8))) short short8;
typedef __attribute__((ext_vector_type(4))) float f32x4;

#define H 8
#define N 384
#define D 32
#define CIN 256
#define HNN (H * N * N)
#define SCALER 0.17677669529663687f
#define EPS 1e-9f
#define SHIFT 5.0f   // constant stabilization shift; cancels exactly in Num/Den ratio

// workspace float offsets
#define S_OFF    491520u         // only plane 1 used: Y[k][i] = exp(y-SHIFT), fp32
#define VJT_OFF  4030464u        // H*D*N: vj transposed [h][d][n]
#define VKT_OFF  4128768u        // H*D*N
#define NUM_OFF  4233224u        // H*N*D
#define DEN_OFF  4331528u        // H*N
#define XBF_OFF  4334600u        // ushort[H*N*N]: exp(X)-packed in MFMA-frag order
#define ZBF_OFF  4924424u        // ushort[H*N*N]: exp(Z) bf16 row-major
#define LBF_OFF  5523464u        // u16[3*H*N*D]: bf16 a,b,c for scores MFMA

__device__ inline float bf2f(u16 u) {
    union { unsigned int x; float f; } c; c.x = ((unsigned int)u) << 16; return c.f;
}
__device__ inline u16 f2bf(float f) {
    unsigned int x = __float_as_uint(f);
    return (u16)((x + 0x7FFFu + ((x >> 16) & 1u)) >> 16);
}

// ---------------- K1: projection GEMM  wx[n,m] = sum_k hs[n,k]*W[m,k] ----------------
__global__ __launch_bounds__(256) void proj_kernel(const float* __restrict__ hs,
                                                   const float* __restrict__ W,
                                                   float* __restrict__ projT,
                                                   u16* __restrict__ Lbf) {
    __shared__ float hs_s[64][68];
    __shared__ float w_s[64][68];
    const int tid = threadIdx.x;
    const int tx = tid & 15, ty = tid >> 4;
    const int m0 = blockIdx.x * 64, n0 = blockIdx.y * 64;
    float acc[4][4] = {};
    for (int k0 = 0; k0 < CIN; k0 += 64) {
        __syncthreads();
#pragma unroll
        for (int rep = 0; rep < 4; ++rep) {
            int lin = rep * 1024 + tid * 4;
            int rl = lin >> 6, kl = lin & 63;
            float4 hv = *(const float4*)&hs[(n0 + rl) * CIN + k0 + kl];
            hs_s[kl + 0][rl] = hv.x; hs_s[kl + 1][rl] = hv.y;
            hs_s[kl + 2][rl] = hv.z; hs_s[kl + 3][rl] = hv.w;
            float4 wv = *(const float4*)&W[(m0 + rl) * CIN + k0 + kl];
            w_s[kl + 0][rl] = wv.x; w_s[kl + 1][rl] = wv.y;
            w_s[kl + 2][rl] = wv.z; w_s[kl + 3][rl] = wv.w;
        }
        __syncthreads();
#pragma unroll 16
        for (int kk = 0; kk < 64; ++kk) {
            float4 a4 = *(const float4*)&hs_s[kk][ty * 4];
            float4 b4 = *(const float4*)&w_s[kk][tx * 4];
            float av[4] = {a4.x, a4.y, a4.z, a4.w};
            float bv[4] = {b4.x, b4.y, b4.z, b4.w};
#pragma unroll
            for (int a_ = 0; a_ < 4; ++a_) {
#pragma unroll
                for (int b_ = 0; b_ < 4; ++b_) {
                    acc[a_][b_] = fmaf(av[a_], bv[b_], acc[a_][b_]);
                }
            }
        }
    }
#pragma unroll
    for (int a_ = 0; a_ < 4; ++a_) {
        int n = n0 + ty * 4 + a_;
#pragma unroll
        for (int b_ = 0; b_ < 4; ++b_) {
            int m = m0 + tx * 4 + b_;
            int s = m >> 8, hh = (m >> 5) & 7, d = m & 31;
            if (s >= 3) projT[(s - 3) * (H * D * N) + hh * (D * N) + d * N + n] = acc[a_][b_];
            else        Lbf[((s * H + hh) * N + n) * D + d] = f2bf(acc[a_][b_]);
        }
    }
}

// ---------------- K2: scores via MFMA bf16 + FUSED exp(S - SHIFT) ----------------
__global__ __launch_bounds__(256) void scores_mfma(const u16* __restrict__ Lbf,
                                                   float* __restrict__ Y,
                                                   u16* __restrict__ Xbf,
                                                   u16* __restrict__ Zbf) {
    const int tid = threadIdx.x;
    const int w = tid >> 6, lane = tid & 63;
    const int l15 = lane & 15, lhi = lane >> 4;
    const int r0 = (blockIdx.x % 3) * 128, c0 = (blockIdx.x / 3) * 128;
    const int h = blockIdx.y;
    const int t = blockIdx.z;
    const int Lidx = (t == 2) ? 0 : 2;
    const int Ridx = (t == 1) ? 0 : 1;
    const u16* Lp = Lbf + ((Lidx * H + h) * N) * D;
    const u16* Rp = Lbf + ((Ridx * H + h) * N) * D;

    short8 a[2], b[8];
#pragma unroll
    for (int fi = 0; fi < 2; ++fi)
        a[fi] = *(const short8*)&Lp[(r0 + w * 32 + fi * 16 + l15) * D + lhi * 8];
#pragma unroll
    for (int fk = 0; fk < 8; ++fk)
        b[fk] = *(const short8*)&Rp[(c0 + fk * 16 + l15) * D + lhi * 8];

    f32x4 acc[2][8];
#pragma unroll
    for (int fi = 0; fi < 2; ++fi)
#pragma unroll
        for (int fk = 0; fk < 8; ++fk) {
            acc[fi][fk] = (f32x4){0.f, 0.f, 0.f, 0.f};
            acc[fi][fk] = __builtin_amdgcn_mfma_f32_16x16x32_bf16(a[fi], b[fk], acc[fi][fk], 0, 0, 0);
        }

    if (t == 1) {
        float* Yp = Y + h * (N * N);
#pragma unroll
        for (int fi = 0; fi < 2; ++fi)
#pragma unroll
            for (int reg = 0; reg < 4; ++reg) {
                const int row = r0 + w * 32 + fi * 16 + lhi * 4 + reg;
#pragma unroll
                for (int fk = 0; fk < 8; ++fk)
                    Yp[row * N + c0 + fk * 16 + l15] =
                        __expf(fmaf(acc[fi][fk][reg], SCALER, -SHIFT));
            }
    } else if (t == 0) {
#pragma unroll
        for (int fi = 0; fi < 2; ++fi)
#pragma unroll
            for (int reg = 0; reg < 4; ++reg) {
                const int row = r0 + w * 32 + fi * 16 + lhi * 4 + reg;   // k
                const int kt = row >> 4;
                const int lp_row = row & 15;
#pragma unroll
                for (int fk = 0; fk < 8; ++fk) {
                    const int col = c0 + fk * 16 + l15;                  // j
                    const float e = __expf(fmaf(acc[fi][fk][reg], SCALER, -SHIFT));
                    const int jt = col >> 5;
                    const int lanep = lp_row | (((col >> 3) & 3) << 4);
                    Xbf[(((h * 24 + kt) * 12 + jt) << 9) + lanep * 8 + (col & 7)] = f2bf(e);
                }
            }
    } else {
        u16* Zp = Zbf + h * (N * N);
#pragma unroll
        for (int fi = 0; fi < 2; ++fi)
#pragma unroll
            for (int reg = 0; reg < 4; ++reg) {
                const int row = r0 + w * 32 + fi * 16 + lhi * 4 + reg;
#pragma unroll
                for (int fk = 0; fk < 8; ++fk) {
                    const float e = __expf(fmaf(acc[fi][fk][reg], SCALER, -SHIFT));
                    Zp[row * N + c0 + fk * 16 + l15] = f2bf(e);
                }
            }
    }
}

// ---------------- K3: cubic contraction via MFMA bf16, v18 (8 waves x 48k, 2.5 blocks/CU) ----------------
// block = (h, i-tile of 32, d-group of 2). 512 thr = 8 waves; wave w owns k in [w*48,+48)
// (fk=3). Per js: 4 A LDS reads + 3 coalesced B loads + 12 MFMAs. acc=48 f32.
// launch_bounds(512,5): cap 102 regs (~100 used) -> 5 waves/SIMD = 20 waves/CU = 2.5 blocks.
// Tripwire: WRITE_SIZE (spill).
__global__ __launch_bounds__(512, 5) void cubic_mfma(
        const u16* __restrict__ Xbf, const u16* __restrict__ Zbf,
        const float* __restrict__ Y, const float* __restrict__ vjT,
        const float* __restrict__ vkT, float* __restrict__ NumB,
        float* __restrict__ DenB) {
    const int orig = blockIdx.x;             // 0..1631 (1632 = 8 x 204, bijective)
    const int wg = (orig & 7) * 204 + (orig >> 3);
    const int h   = wg / 204;                // one head per XCD
    const int rem = wg - h * 204;
    const int dg  = rem / 12;                // 0..16
    const int it12 = rem - dg * 12;          // 0..11
    const int i0  = it12 * 32;
    const bool dgden = (dg == 16);
    const int d0 = dgden ? 0 : 2 * dg;
    const int d1 = dgden ? 0 : 2 * dg + 1;
    const int tid = threadIdx.x;
    const int w = tid >> 6, lane = tid & 63;
    __shared__ u16 A_lds[2 * 32 * N];        // [t][f(24)][64][8] frag-packed (48 KB)
    __shared__ float red[2][8][32];
    u16* A0 = A_lds;
    u16* A1 = A_lds + 32 * N;
    const u16* Zh = Zbf + h * (N * N);
    const float* Yh = Y + h * (N * N);       // Y[k][i]
    const float* vjd0 = vjT + h * (D * N) + d0 * N;
    const float* vjd1 = vjT + h * (D * N) + d1 * N;
    const float* vkd0 = vkT + h * (D * N) + d0 * N;
    const float* vkd1 = vkT + h * (D * N) + d1 * N;

    // ---- A-prep: coalesced global reads, frag-packed LDS writes (both tiles)
    // 1536 chunks(short8); 3 iters x 512 thr
    {
#pragma unroll
        for (int it = 0; it < 3; ++it) {
            const int g = it * 512 + tid;        // 0..1535
            const int row = g / 48;              // 0..31
            const int cb = g - row * 48;
            const int jb = cb * 8;
            const int fi = row >> 4, l15r = row & 15;
            const int js = cb >> 2, sub = cb & 3;
            const int f = fi * 12 + js;          // 0..23
            const int dst = f * 512 + (((l15r | (sub << 4)) ^ (f & 7)) << 3);
            short8 zv = *(const short8*)&Zh[(i0 + row) * N + jb];
            if (dgden) {
                *(short8*)&A0[dst] = zv;
                *(short8*)&A1[dst] = zv;
            } else {
                float4 p0 = *(const float4*)&vjd0[jb];
                float4 p1 = *(const float4*)&vjd0[jb + 4];
                float4 q0 = *(const float4*)&vjd1[jb];
                float4 q1 = *(const float4*)&vjd1[jb + 4];
                float v0[8] = {p0.x, p0.y, p0.z, p0.w, p1.x, p1.y, p1.z, p1.w};
                float v1[8] = {q0.x, q0.y, q0.z, q0.w, q1.x, q1.y, q1.z, q1.w};
                short8 o0, o1;
#pragma unroll
                for (int e = 0; e < 8; ++e) {
                    float zf = bf2f((u16)zv[e]);
                    o0[e] = (short)f2bf(zf * v0[e]);
                    o1[e] = (short)f2bf(zf * v1[e]);
                }
                *(short8*)&A0[dst] = o0;
                *(short8*)&A1[dst] = o1;
            }
        }
    }
    __syncthreads();

    // ---- MFMA main loop: no barriers, k held in accumulators
    f32x4 acc0[2][3], acc1[2][3];
#pragma unroll
    for (int fi = 0; fi < 2; ++fi)
#pragma unroll
        for (int fk = 0; fk < 3; ++fk) {
            acc0[fi][fk] = (f32x4){0.f, 0.f, 0.f, 0.f};
            acc1[fi][fk] = (f32x4){0.f, 0.f, 0.f, 0.f};
        }

    const int l15 = lane & 15;
    // packed-B: wave w covers k-tiles 3w..3w+2; frag (kt, jt) at (kt*12+jt)*512
    const u16* Bp = Xbf + ((h * 24 + w * 3) * 12 << 9) + lane * 8;
    const int KTS = 12 * 512;         // k-tile stride (u16)

#pragma unroll
    for (int js = 0; js < 12; ++js) {
        short8 a0[2], a1[2];
#pragma unroll
        for (int fi = 0; fi < 2; ++fi) {
            const int f = fi * 12 + js;
            const int off = f * 512 + ((lane ^ (f & 7)) << 3);
            a0[fi] = *(const short8*)&A0[off];
            a1[fi] = *(const short8*)&A1[off];
        }
        short8 b[3];
#pragma unroll
        for (int fk = 0; fk < 3; ++fk)
            b[fk] = *(const short8*)&Bp[fk * KTS + js * 512];
        __builtin_amdgcn_s_setprio(1);
#pragma unroll
        for (int fk = 0; fk < 3; ++fk) {
#pragma unroll
            for (int fi = 0; fi < 2; ++fi) {
                acc0[fi][fk] = __builtin_amdgcn_mfma_f32_16x16x32_bf16(a0[fi], b[fk], acc0[fi][fk], 0, 0, 0);
                acc1[fi][fk] = __builtin_amdgcn_mfma_f32_16x16x32_bf16(a1[fi], b[fk], acc1[fi][fk], 0, 0, 0);
            }
        }
        __builtin_amdgcn_s_setprio(0);
    }

    // ---- epilogue (merged d0/d1): Y[k][i] contiguous float4 loads, weight, k-reduce
    const int rbase = (lane >> 4) << 2;
    float np0[2][4], np1[2][4];
#pragma unroll
    for (int fi = 0; fi < 2; ++fi)
#pragma unroll
        for (int reg = 0; reg < 4; ++reg) { np0[fi][reg] = 0.f; np1[fi][reg] = 0.f; }
#pragma unroll
    for (int fk = 0; fk < 3; ++fk) {
        const int kcol = w * 48 + fk * 16 + l15;
        const float vk0 = dgden ? 1.0f : vkd0[kcol];
        const float vk1 = dgden ? 1.0f : vkd1[kcol];
#pragma unroll
        for (int fi = 0; fi < 2; ++fi) {
            const float4 yv = *(const float4*)&Yh[kcol * N + i0 + fi * 16 + rbase];
            const float yarr[4] = {yv.x, yv.y, yv.z, yv.w};
#pragma unroll
            for (int reg = 0; reg < 4; ++reg) {
                np0[fi][reg] = fmaf(acc0[fi][fk][reg], yarr[reg] * vk0, np0[fi][reg]);
                np1[fi][reg] = fmaf(acc1[fi][fk][reg], yarr[reg] * vk1, np1[fi][reg]);
            }
        }
    }
#pragma unroll
    for (int fi = 0; fi < 2; ++fi) {
#pragma unroll
        for (int reg = 0; reg < 4; ++reg) {
            float v0 = np0[fi][reg];
            v0 += __shfl_xor(v0, 1); v0 += __shfl_xor(v0, 2);
            v0 += __shfl_xor(v0, 4); v0 += __shfl_xor(v0, 8);
            np0[fi][reg] = v0;
            float v1 = np1[fi][reg];
            v1 += __shfl_xor(v1, 1); v1 += __shfl_xor(v1, 2);
            v1 += __shfl_xor(v1, 4); v1 += __shfl_xor(v1, 8);
            np1[fi][reg] = v1;
        }
    }
    if (l15 == 0) {
#pragma unroll
        for (int fi = 0; fi < 2; ++fi)
#pragma unroll
            for (int reg = 0; reg < 4; ++reg) {
                red[0][w][fi * 16 + rbase + reg] = np0[fi][reg];
                red[1][w][fi * 16 + rbase + reg] = np1[fi][reg];
            }
    }
    __syncthreads();
    if (tid < 32) {
        float s = 0.f;
#pragma unroll
        for (int ww = 0; ww < 8; ++ww) s += red[0][ww][tid];
        if (!dgden) NumB[h * (N * D) + (i0 + tid) * D + 2 * dg] = s;
        else        DenB[h * N + i0 + tid] = s;
    } else if (tid < 64 && !dgden) {
        const int i = tid - 32;
        float s = 0.f;
#pragma unroll
        for (int ww = 0; ww < 8; ++ww) s += red[1][ww][i];
        NumB[h * (N * D) + (i0 + i) * D + 2 * dg + 1] = s;
    }
}

// ---------------- K4: normalize + fp32 output [n, h*D+d] ----------------
__global__ void out_kernel(const float* __restrict__ NumB, const float* __restrict__ DenB,
                           float* __restrict__ out) {
    int idx = blockIdx.x * 256 + threadIdx.x;  // 0..98303
    int n = idx >> 8;
    int ch = idx & 255;
    int hh = ch >> 5, d = ch & 31;
    float v = NumB[hh * (N * D) + n * D + d] / (DenB[hh * N + n] + EPS);
    out[idx] = v;
}

extern "C" void kernel_launch(void* const* d_in, const int* in_sizes, int n_in,
                              void* d_out, int out_size, void* d_ws, size_t ws_size,
                              hipStream_t stream) {
    const float* hs = (const float*)d_in[0];
    const float* W  = (const float*)d_in[1];
    float* ws = (float*)d_ws;
    float* Yp    = ws + S_OFF + HNN;   // plane 1 of the old S buffer: Y[k][i]
    float* projT = ws + VJT_OFF;       // vj rows, then vk rows at +H*D*N
    float* NumB  = ws + NUM_OFF;
    float* DenB  = ws + DEN_OFF;
    u16*   Xbf   = (u16*)(ws + XBF_OFF);
    u16*   Zbf   = (u16*)(ws + ZBF_OFF);
    u16*   Lbf   = (u16*)(ws + LBF_OFF);
    float* out = (float*)d_out;

    proj_kernel<<<dim3(20, 6), 256, 0, stream>>>(hs, W, projT, Lbf);
    scores_mfma<<<dim3(9, 8, 3), 256, 0, stream>>>(Lbf, Yp, Xbf, Zbf);
    cubic_mfma<<<dim3(1632), 512, 0, stream>>>(Xbf, Zbf, Yp, ws + VJT_OFF,
                                               ws + VKT_OFF, NumB, DenB);
    out_kernel<<<(H * N * D) / 256, 256, 0, stream>>>(NumB, DenB, out);
}

// Round 22
// 74.376 us; speedup vs baseline: 1.2618x; 1.0173x over previous
//
#include <hip/hip_runtime.h>
#include <hip/hip_bf16.h>

typedef unsigned short u16;
typedef unsigned int u32;
typedef __attribute__((ext_vector_type(8))) short short8;
typedef __attribute__((ext_vector_type(4))) float f32x4;

#define H 8
#define N 384
#define D 32
#define CIN 256
#define HNN (H * N * N)
#define SCALER 0.17677669529663687f
#define EPS 1e-9f
#define SHIFT 5.0f   // constant stabilization shift; cancels exactly in Num/Den ratio

// workspace float offsets
#define S_OFF    491520u         // only plane 1 used: Y[k][i] = exp(y-SHIFT), fp32
#define VJT_OFF  4030464u        // H*D*N: vj transposed [h][d][n]
#define VKT_OFF  4128768u        // H*D*N
#define NUM_OFF  4233224u        // H*N*D
#define DEN_OFF  4331528u        // H*N
#define XBF_OFF  4334600u        // ushort[H*N*N]: exp(X)-packed in MFMA-frag order
#define ZBF_OFF  4924424u        // ushort[H*N*N]: exp(Z) bf16 row-major
#define LBF_OFF  5523464u        // u16[3*H*N*D]: bf16 a,b,c for scores MFMA

__device__ inline float bf2f(u16 u) {
    union { unsigned int x; float f; } c; c.x = ((unsigned int)u) << 16; return c.f;
}
__device__ inline u16 f2bf(float f) {
    unsigned int x = __float_as_uint(f);
    return (u16)((x + 0x7FFFu + ((x >> 16) & 1u)) >> 16);
}

// ---------------- K1: projection GEMM  wx[n,m] = sum_k hs[n,k]*W[m,k] ----------------
__global__ __launch_bounds__(256) void proj_kernel(const float* __restrict__ hs,
                                                   const float* __restrict__ W,
                                                   float* __restrict__ projT,
                                                   u16* __restrict__ Lbf) {
    __shared__ float hs_s[64][68];
    __shared__ float w_s[64][68];
    const int tid = threadIdx.x;
    const int tx = tid & 15, ty = tid >> 4;
    const int m0 = blockIdx.x * 64, n0 = blockIdx.y * 64;
    float acc[4][4] = {};
    for (int k0 = 0; k0 < CIN; k0 += 64) {
        __syncthreads();
#pragma unroll
        for (int rep = 0; rep < 4; ++rep) {
            int lin = rep * 1024 + tid * 4;
            int rl = lin >> 6, kl = lin & 63;
            float4 hv = *(const float4*)&hs[(n0 + rl) * CIN + k0 + kl];
            hs_s[kl + 0][rl] = hv.x; hs_s[kl + 1][rl] = hv.y;
            hs_s[kl + 2][rl] = hv.z; hs_s[kl + 3][rl] = hv.w;
            float4 wv = *(const float4*)&W[(m0 + rl) * CIN + k0 + kl];
            w_s[kl + 0][rl] = wv.x; w_s[kl + 1][rl] = wv.y;
            w_s[kl + 2][rl] = wv.z; w_s[kl + 3][rl] = wv.w;
        }
        __syncthreads();
#pragma unroll 16
        for (int kk = 0; kk < 64; ++kk) {
            float4 a4 = *(const float4*)&hs_s[kk][ty * 4];
            float4 b4 = *(const float4*)&w_s[kk][tx * 4];
            float av[4] = {a4.x, a4.y, a4.z, a4.w};
            float bv[4] = {b4.x, b4.y, b4.z, b4.w};
#pragma unroll
            for (int a_ = 0; a_ < 4; ++a_) {
#pragma unroll
                for (int b_ = 0; b_ < 4; ++b_) {
                    acc[a_][b_] = fmaf(av[a_], bv[b_], acc[a_][b_]);
                }
            }
        }
    }
#pragma unroll
    for (int a_ = 0; a_ < 4; ++a_) {
        int n = n0 + ty * 4 + a_;
#pragma unroll
        for (int b_ = 0; b_ < 4; ++b_) {
            int m = m0 + tx * 4 + b_;
            int s = m >> 8, hh = (m >> 5) & 7, d = m & 31;
            if (s >= 3) projT[(s - 3) * (H * D * N) + hh * (D * N) + d * N + n] = acc[a_][b_];
            else        Lbf[((s * H + hh) * N + n) * D + d] = f2bf(acc[a_][b_]);
        }
    }
}

// ---------------- K2: scores via MFMA bf16 + FUSED exp(S - SHIFT) ----------------
__global__ __launch_bounds__(256) void scores_mfma(const u16* __restrict__ Lbf,
                                                   float* __restrict__ Y,
                                                   u16* __restrict__ Xbf,
                                                   u16* __restrict__ Zbf) {
    const int tid = threadIdx.x;
    const int w = tid >> 6, lane = tid & 63;
    const int l15 = lane & 15, lhi = lane >> 4;
    const int r0 = (blockIdx.x % 3) * 128, c0 = (blockIdx.x / 3) * 128;
    const int h = blockIdx.y;
    const int t = blockIdx.z;
    const int Lidx = (t == 2) ? 0 : 2;
    const int Ridx = (t == 1) ? 0 : 1;
    const u16* Lp = Lbf + ((Lidx * H + h) * N) * D;
    const u16* Rp = Lbf + ((Ridx * H + h) * N) * D;

    short8 a[2], b[8];
#pragma unroll
    for (int fi = 0; fi < 2; ++fi)
        a[fi] = *(const short8*)&Lp[(r0 + w * 32 + fi * 16 + l15) * D + lhi * 8];
#pragma unroll
    for (int fk = 0; fk < 8; ++fk)
        b[fk] = *(const short8*)&Rp[(c0 + fk * 16 + l15) * D + lhi * 8];

    f32x4 acc[2][8];
#pragma unroll
    for (int fi = 0; fi < 2; ++fi)
#pragma unroll
        for (int fk = 0; fk < 8; ++fk) {
            acc[fi][fk] = (f32x4){0.f, 0.f, 0.f, 0.f};
            acc[fi][fk] = __builtin_amdgcn_mfma_f32_16x16x32_bf16(a[fi], b[fk], acc[fi][fk], 0, 0, 0);
        }

    if (t == 1) {
        float* Yp = Y + h * (N * N);
#pragma unroll
        for (int fi = 0; fi < 2; ++fi)
#pragma unroll
            for (int reg = 0; reg < 4; ++reg) {
                const int row = r0 + w * 32 + fi * 16 + lhi * 4 + reg;
#pragma unroll
                for (int fk = 0; fk < 8; ++fk)
                    Yp[row * N + c0 + fk * 16 + l15] =
                        __expf(fmaf(acc[fi][fk][reg], SCALER, -SHIFT));
            }
    } else if (t == 0) {
#pragma unroll
        for (int fi = 0; fi < 2; ++fi)
#pragma unroll
            for (int reg = 0; reg < 4; ++reg) {
                const int row = r0 + w * 32 + fi * 16 + lhi * 4 + reg;   // k
                const int kt = row >> 4;
                const int lp_row = row & 15;
#pragma unroll
                for (int fk = 0; fk < 8; ++fk) {
                    const int col = c0 + fk * 16 + l15;                  // j
                    const float e = __expf(fmaf(acc[fi][fk][reg], SCALER, -SHIFT));
                    const int jt = col >> 5;
                    const int lanep = lp_row | (((col >> 3) & 3) << 4);
                    Xbf[(((h * 24 + kt) * 12 + jt) << 9) + lanep * 8 + (col & 7)] = f2bf(e);
                }
            }
    } else {
        u16* Zp = Zbf + h * (N * N);
#pragma unroll
        for (int fi = 0; fi < 2; ++fi)
#pragma unroll
            for (int reg = 0; reg < 4; ++reg) {
                const int row = r0 + w * 32 + fi * 16 + lhi * 4 + reg;
#pragma unroll
                for (int fk = 0; fk < 8; ++fk) {
                    const float e = __expf(fmaf(acc[fi][fk][reg], SCALER, -SHIFT));
                    Zp[row * N + c0 + fk * 16 + l15] = f2bf(e);
                }
            }
    }
}

// ---------------- K3: cubic contraction via MFMA bf16, v19 (fk=6: half LDS per MFMA) ----------------
// block = (h, i-tile of 32, d-group of 2). 256 thr = 4 waves; wave w owns k in [w*96,+96)
// (fk=6 packed-B k-tiles 6w..6w+5). Per js: 4 A LDS reads + 6 B loads + 24 MFMAs ->
// LDS/MFMA = 0.167 KB (r21 was 0.33) -> LDS ~384 cyc vs MFMA ~345 cyc per CU-js: balanced.
// Regs ~145 <= 170 (256,3) -> 12 waves/CU = 3 blocks/CU. Tripwire: WRITE_SIZE ~0.4 MB.
__global__ __launch_bounds__(256, 3) void cubic_mfma(
        const u16* __restrict__ Xbf, const u16* __restrict__ Zbf,
        const float* __restrict__ Y, const float* __restrict__ vjT,
        const float* __restrict__ vkT, float* __restrict__ NumB,
        float* __restrict__ DenB) {
    const int orig = blockIdx.x;             // 0..1631 (1632 = 8 x 204, bijective)
    const int wg = (orig & 7) * 204 + (orig >> 3);
    const int h   = wg / 204;                // one head per XCD
    const int rem = wg - h * 204;
    const int dg  = rem / 12;                // 0..16
    const int it12 = rem - dg * 12;          // 0..11
    const int i0  = it12 * 32;
    const bool dgden = (dg == 16);
    const int d0 = dgden ? 0 : 2 * dg;
    const int d1 = dgden ? 0 : 2 * dg + 1;
    const int tid = threadIdx.x;
    const int w = tid >> 6, lane = tid & 63;
    __shared__ u16 A_lds[2 * 32 * N];        // [t][f(24)][64][8] frag-packed (48 KB)
    __shared__ float red[2][4][32];
    u16* A0 = A_lds;
    u16* A1 = A_lds + 32 * N;
    const u16* Zh = Zbf + h * (N * N);
    const float* Yh = Y + h * (N * N);       // Y[k][i]
    const float* vjd0 = vjT + h * (D * N) + d0 * N;
    const float* vjd1 = vjT + h * (D * N) + d1 * N;
    const float* vkd0 = vkT + h * (D * N) + d0 * N;
    const float* vkd1 = vkT + h * (D * N) + d1 * N;

    // ---- A-prep: coalesced global reads, frag-packed LDS writes (both tiles)
    // 1536 chunks(short8); 6 iters x 256 thr
    {
#pragma unroll
        for (int it = 0; it < 6; ++it) {
            const int g = it * 256 + tid;        // 0..1535
            const int row = g / 48;              // 0..31
            const int cb = g - row * 48;
            const int jb = cb * 8;
            const int fi = row >> 4, l15r = row & 15;
            const int js = cb >> 2, sub = cb & 3;
            const int f = fi * 12 + js;          // 0..23
            const int dst = f * 512 + (((l15r | (sub << 4)) ^ (f & 7)) << 3);
            short8 zv = *(const short8*)&Zh[(i0 + row) * N + jb];
            if (dgden) {
                *(short8*)&A0[dst] = zv;
                *(short8*)&A1[dst] = zv;
            } else {
                float4 p0 = *(const float4*)&vjd0[jb];
                float4 p1 = *(const float4*)&vjd0[jb + 4];
                float4 q0 = *(const float4*)&vjd1[jb];
                float4 q1 = *(const float4*)&vjd1[jb + 4];
                float v0[8] = {p0.x, p0.y, p0.z, p0.w, p1.x, p1.y, p1.z, p1.w};
                float v1[8] = {q0.x, q0.y, q0.z, q0.w, q1.x, q1.y, q1.z, q1.w};
                short8 o0, o1;
#pragma unroll
                for (int e = 0; e < 8; ++e) {
                    float zf = bf2f((u16)zv[e]);
                    o0[e] = (short)f2bf(zf * v0[e]);
                    o1[e] = (short)f2bf(zf * v1[e]);
                }
                *(short8*)&A0[dst] = o0;
                *(short8*)&A1[dst] = o1;
            }
        }
    }
    __syncthreads();

    // ---- MFMA main loop: no barriers, k held in accumulators
    f32x4 acc0[2][6], acc1[2][6];
#pragma unroll
    for (int fi = 0; fi < 2; ++fi)
#pragma unroll
        for (int fk = 0; fk < 6; ++fk) {
            acc0[fi][fk] = (f32x4){0.f, 0.f, 0.f, 0.f};
            acc1[fi][fk] = (f32x4){0.f, 0.f, 0.f, 0.f};
        }

    const int l15 = lane & 15;
    // packed-B: wave w covers k-tiles 6w..6w+5; frag (kt, jt) at (kt*12+jt)*512
    const u16* Bp = Xbf + ((h * 24 + w * 6) * 12 << 9) + lane * 8;
    const int KTS = 12 * 512;         // k-tile stride (u16)

#pragma unroll
    for (int js = 0; js < 12; ++js) {
        short8 a0[2], a1[2];
#pragma unroll
        for (int fi = 0; fi < 2; ++fi) {
            const int f = fi * 12 + js;
            const int off = f * 512 + ((lane ^ (f & 7)) << 3);
            a0[fi] = *(const short8*)&A0[off];
            a1[fi] = *(const short8*)&A1[off];
        }
        short8 b[6];
#pragma unroll
        for (int fk = 0; fk < 6; ++fk)
            b[fk] = *(const short8*)&Bp[fk * KTS + js * 512];
        __builtin_amdgcn_s_setprio(1);
#pragma unroll
        for (int fk = 0; fk < 6; ++fk) {
#pragma unroll
            for (int fi = 0; fi < 2; ++fi) {
                acc0[fi][fk] = __builtin_amdgcn_mfma_f32_16x16x32_bf16(a0[fi], b[fk], acc0[fi][fk], 0, 0, 0);
                acc1[fi][fk] = __builtin_amdgcn_mfma_f32_16x16x32_bf16(a1[fi], b[fk], acc1[fi][fk], 0, 0, 0);
            }
        }
        __builtin_amdgcn_s_setprio(0);
    }

    // ---- epilogue (merged d0/d1): Y[k][i] contiguous float4 loads, weight, k-reduce
    const int rbase = (lane >> 4) << 2;
    float np0[2][4], np1[2][4];
#pragma unroll
    for (int fi = 0; fi < 2; ++fi)
#pragma unroll
        for (int reg = 0; reg < 4; ++reg) { np0[fi][reg] = 0.f; np1[fi][reg] = 0.f; }
#pragma unroll
    for (int fk = 0; fk < 6; ++fk) {
        const int kcol = w * 96 + fk * 16 + l15;
        const float vk0 = dgden ? 1.0f : vkd0[kcol];
        const float vk1 = dgden ? 1.0f : vkd1[kcol];
#pragma unroll
        for (int fi = 0; fi < 2; ++fi) {
            const float4 yv = *(const float4*)&Yh[kcol * N + i0 + fi * 16 + rbase];
            const float yarr[4] = {yv.x, yv.y, yv.z, yv.w};
#pragma unroll
            for (int reg = 0; reg < 4; ++reg) {
                np0[fi][reg] = fmaf(acc0[fi][fk][reg], yarr[reg] * vk0, np0[fi][reg]);
                np1[fi][reg] = fmaf(acc1[fi][fk][reg], yarr[reg] * vk1, np1[fi][reg]);
            }
        }
    }
#pragma unroll
    for (int fi = 0; fi < 2; ++fi) {
#pragma unroll
        for (int reg = 0; reg < 4; ++reg) {
            float v0 = np0[fi][reg];
            v0 += __shfl_xor(v0, 1); v0 += __shfl_xor(v0, 2);
            v0 += __shfl_xor(v0, 4); v0 += __shfl_xor(v0, 8);
            np0[fi][reg] = v0;
            float v1 = np1[fi][reg];
            v1 += __shfl_xor(v1, 1); v1 += __shfl_xor(v1, 2);
            v1 += __shfl_xor(v1, 4); v1 += __shfl_xor(v1, 8);
            np1[fi][reg] = v1;
        }
    }
    if (l15 == 0) {
#pragma unroll
        for (int fi = 0; fi < 2; ++fi)
#pragma unroll
            for (int reg = 0; reg < 4; ++reg) {
                red[0][w][fi * 16 + rbase + reg] = np0[fi][reg];
                red[1][w][fi * 16 + rbase + reg] = np1[fi][reg];
            }
    }
    __syncthreads();
    if (tid < 32) {
        float s = 0.f;
#pragma unroll
        for (int ww = 0; ww < 4; ++ww) s += red[0][ww][tid];
        if (!dgden) NumB[h * (N * D) + (i0 + tid) * D + 2 * dg] = s;
        else        DenB[h * N + i0 + tid] = s;
    } else if (tid < 64 && !dgden) {
        const int i = tid - 32;
        float s = 0.f;
#pragma unroll
        for (int ww = 0; ww < 4; ++ww) s += red[1][ww][i];
        NumB[h * (N * D) + (i0 + i) * D + 2 * dg + 1] = s;
    }
}

// ---------------- K4: normalize + fp32 output [n, h*D+d] ----------------
__global__ void out_kernel(const float* __restrict__ NumB, const float* __restrict__ DenB,
                           float* __restrict__ out) {
    int idx = blockIdx.x * 256 + threadIdx.x;  // 0..98303
    int n = idx >> 8;
    int ch = idx & 255;
    int hh = ch >> 5, d = ch & 31;
    float v = NumB[hh * (N * D) + n * D + d] / (DenB[hh * N + n] + EPS);
    out[idx] = v;
}

extern "C" void kernel_launch(void* const* d_in, const int* in_sizes, int n_in,
                              void* d_out, int out_size, void* d_ws, size_t ws_size,
                              hipStream_t stream) {
    const float* hs = (const float*)d_in[0];
    const float* W  = (const float*)d_in[1];
    float* ws = (float*)d_ws;
    float* Yp    = ws + S_OFF + HNN;   // plane 1 of the old S buffer: Y[k][i]
    float* projT = ws + VJT_OFF;       // vj rows, then vk rows at +H*D*N
    float* NumB  = ws + NUM_OFF;
    float* DenB  = ws + DEN_OFF;
    u16*   Xbf   = (u16*)(ws + XBF_OFF);
    u16*   Zbf   = (u16*)(ws + ZBF_OFF);
    u16*   Lbf   = (u16*)(ws + LBF_OFF);
    float* out = (float*)d_out;

    proj_kernel<<<dim3(20, 6), 256, 0, stream>>>(hs, W, projT, Lbf);
    scores_mfma<<<dim3(9, 8, 3), 256, 0, stream>>>(Lbf, Yp, Xbf, Zbf);
    cubic_mfma<<<dim3(1632), 256, 0, stream>>>(Xbf, Zbf, Yp, ws + VJT_OFF,
                                               ws + VKT_OFF, NumB, DenB);
    out_kernel<<<(H * N * D) / 256, 256, 0, stream>>>(NumB, DenB, out);
}

// Round 23
// 71.106 us; speedup vs baseline: 1.3198x; 1.0460x over previous
//
#include <hip/hip_runtime.h>
#include <hip/hip_bf16.h>

typedef unsigned short u16;
typedef unsigned int u32;
typedef __attribute__((ext_vector_type(8))) short short8;
typedef __attribute__((ext_vector_type(4))) float f32x4;

#define H 8
#define N 384
#define D 32
#define CIN 256
#define HNN (H * N * N)
#define SCALER 0.17677669529663687f
#define EPS 1e-9f
#define SHIFT 5.0f   // constant stabilization shift; cancels exactly in Num/Den ratio

// workspace float offsets
#define S_OFF    491520u         // only plane 1 used: Y[k][i] = exp(y-SHIFT), fp32
#define VJT_OFF  4030464u        // H*D*N: vj transposed [h][d][n]
#define VKT_OFF  4128768u        // H*D*N
#define NUM_OFF  4233224u        // H*N*D
#define DEN_OFF  4331528u        // H*N
#define XBF_OFF  4334600u        // ushort[H*N*N]: exp(X)-packed in MFMA-frag order
#define ZBF_OFF  4924424u        // ushort[H*N*N]: exp(Z) bf16 row-major
#define LBF_OFF  5523464u        // u16[3*H*N*D]: bf16 a,b,c for scores MFMA

__device__ inline float bf2f(u16 u) {
    union { unsigned int x; float f; } c; c.x = ((unsigned int)u) << 16; return c.f;
}
__device__ inline u16 f2bf(float f) {
    unsigned int x = __float_as_uint(f);
    return (u16)((x + 0x7FFFu + ((x >> 16) & 1u)) >> 16);
}

// ---------------- K1: projection GEMM  wx[n,m] = sum_k hs[n,k]*W[m,k] ----------------
__global__ __launch_bounds__(256) void proj_kernel(const float* __restrict__ hs,
                                                   const float* __restrict__ W,
                                                   float* __restrict__ projT,
                                                   u16* __restrict__ Lbf) {
    __shared__ float hs_s[64][68];
    __shared__ float w_s[64][68];
    const int tid = threadIdx.x;
    const int tx = tid & 15, ty = tid >> 4;
    const int m0 = blockIdx.x * 64, n0 = blockIdx.y * 64;
    float acc[4][4] = {};
    for (int k0 = 0; k0 < CIN; k0 += 64) {
        __syncthreads();
#pragma unroll
        for (int rep = 0; rep < 4; ++rep) {
            int lin = rep * 1024 + tid * 4;
            int rl = lin >> 6, kl = lin & 63;
            float4 hv = *(const float4*)&hs[(n0 + rl) * CIN + k0 + kl];
            hs_s[kl + 0][rl] = hv.x; hs_s[kl + 1][rl] = hv.y;
            hs_s[kl + 2][rl] = hv.z; hs_s[kl + 3][rl] = hv.w;
            float4 wv = *(const float4*)&W[(m0 + rl) * CIN + k0 + kl];
            w_s[kl + 0][rl] = wv.x; w_s[kl + 1][rl] = wv.y;
            w_s[kl + 2][rl] = wv.z; w_s[kl + 3][rl] = wv.w;
        }
        __syncthreads();
#pragma unroll 16
        for (int kk = 0; kk < 64; ++kk) {
            float4 a4 = *(const float4*)&hs_s[kk][ty * 4];
            float4 b4 = *(const float4*)&w_s[kk][tx * 4];
            float av[4] = {a4.x, a4.y, a4.z, a4.w};
            float bv[4] = {b4.x, b4.y, b4.z, b4.w};
#pragma unroll
            for (int a_ = 0; a_ < 4; ++a_) {
#pragma unroll
                for (int b_ = 0; b_ < 4; ++b_) {
                    acc[a_][b_] = fmaf(av[a_], bv[b_], acc[a_][b_]);
                }
            }
        }
    }
#pragma unroll
    for (int a_ = 0; a_ < 4; ++a_) {
        int n = n0 + ty * 4 + a_;
#pragma unroll
        for (int b_ = 0; b_ < 4; ++b_) {
            int m = m0 + tx * 4 + b_;
            int s = m >> 8, hh = (m >> 5) & 7, d = m & 31;
            if (s >= 3) projT[(s - 3) * (H * D * N) + hh * (D * N) + d * N + n] = acc[a_][b_];
            else        Lbf[((s * H + hh) * N + n) * D + d] = f2bf(acc[a_][b_]);
        }
    }
}

// ---------------- K2: scores via MFMA bf16 + FUSED exp(S - SHIFT) ----------------
__global__ __launch_bounds__(256) void scores_mfma(const u16* __restrict__ Lbf,
                                                   float* __restrict__ Y,
                                                   u16* __restrict__ Xbf,
                                                   u16* __restrict__ Zbf) {
    const int tid = threadIdx.x;
    const int w = tid >> 6, lane = tid & 63;
    const int l15 = lane & 15, lhi = lane >> 4;
    const int r0 = (blockIdx.x % 3) * 128, c0 = (blockIdx.x / 3) * 128;
    const int h = blockIdx.y;
    const int t = blockIdx.z;
    const int Lidx = (t == 2) ? 0 : 2;
    const int Ridx = (t == 1) ? 0 : 1;
    const u16* Lp = Lbf + ((Lidx * H + h) * N) * D;
    const u16* Rp = Lbf + ((Ridx * H + h) * N) * D;

    short8 a[2], b[8];
#pragma unroll
    for (int fi = 0; fi < 2; ++fi)
        a[fi] = *(const short8*)&Lp[(r0 + w * 32 + fi * 16 + l15) * D + lhi * 8];
#pragma unroll
    for (int fk = 0; fk < 8; ++fk)
        b[fk] = *(const short8*)&Rp[(c0 + fk * 16 + l15) * D + lhi * 8];

    f32x4 acc[2][8];
#pragma unroll
    for (int fi = 0; fi < 2; ++fi)
#pragma unroll
        for (int fk = 0; fk < 8; ++fk) {
            acc[fi][fk] = (f32x4){0.f, 0.f, 0.f, 0.f};
            acc[fi][fk] = __builtin_amdgcn_mfma_f32_16x16x32_bf16(a[fi], b[fk], acc[fi][fk], 0, 0, 0);
        }

    if (t == 1) {
        float* Yp = Y + h * (N * N);
#pragma unroll
        for (int fi = 0; fi < 2; ++fi)
#pragma unroll
            for (int reg = 0; reg < 4; ++reg) {
                const int row = r0 + w * 32 + fi * 16 + lhi * 4 + reg;
#pragma unroll
                for (int fk = 0; fk < 8; ++fk)
                    Yp[row * N + c0 + fk * 16 + l15] =
                        __expf(fmaf(acc[fi][fk][reg], SCALER, -SHIFT));
            }
    } else if (t == 0) {
#pragma unroll
        for (int fi = 0; fi < 2; ++fi)
#pragma unroll
            for (int reg = 0; reg < 4; ++reg) {
                const int row = r0 + w * 32 + fi * 16 + lhi * 4 + reg;   // k
                const int kt = row >> 4;
                const int lp_row = row & 15;
#pragma unroll
                for (int fk = 0; fk < 8; ++fk) {
                    const int col = c0 + fk * 16 + l15;                  // j
                    const float e = __expf(fmaf(acc[fi][fk][reg], SCALER, -SHIFT));
                    const int jt = col >> 5;
                    const int lanep = lp_row | (((col >> 3) & 3) << 4);
                    Xbf[(((h * 24 + kt) * 12 + jt) << 9) + lanep * 8 + (col & 7)] = f2bf(e);
                }
            }
    } else {
        u16* Zp = Zbf + h * (N * N);
#pragma unroll
        for (int fi = 0; fi < 2; ++fi)
#pragma unroll
            for (int reg = 0; reg < 4; ++reg) {
                const int row = r0 + w * 32 + fi * 16 + lhi * 4 + reg;
#pragma unroll
                for (int fk = 0; fk < 8; ++fk) {
                    const float e = __expf(fmaf(acc[fi][fk][reg], SCALER, -SHIFT));
                    Zp[row * N + c0 + fk * 16 + l15] = f2bf(e);
                }
            }
    }
}

// ---------------- K3: cubic contraction via MFMA bf16, v20 (fk=6, no-spill reg cap) ----------------
// block = (h, i-tile of 32, d-group of 2). 256 thr = 4 waves; wave w owns k in [w*96,+96).
// Per js: 4 A LDS reads + 6 B loads + 24 MFMAs. acc=96 + arch ~84 = ~180 regs.
// launch_bounds(256,2): cap 256 -> NO spill (r22 spilled at cap 170: WRITE 12.7 MB).
// Occupancy same as r22's realized ~2 blocks/CU; trade paper-occupancy for zero scratch.
__global__ __launch_bounds__(256, 2) void cubic_mfma(
        const u16* __restrict__ Xbf, const u16* __restrict__ Zbf,
        const float* __restrict__ Y, const float* __restrict__ vjT,
        const float* __restrict__ vkT, float* __restrict__ NumB,
        float* __restrict__ DenB) {
    const int orig = blockIdx.x;             // 0..1631 (1632 = 8 x 204, bijective)
    const int wg = (orig & 7) * 204 + (orig >> 3);
    const int h   = wg / 204;                // one head per XCD
    const int rem = wg - h * 204;
    const int dg  = rem / 12;                // 0..16
    const int it12 = rem - dg * 12;          // 0..11
    const int i0  = it12 * 32;
    const bool dgden = (dg == 16);
    const int d0 = dgden ? 0 : 2 * dg;
    const int d1 = dgden ? 0 : 2 * dg + 1;
    const int tid = threadIdx.x;
    const int w = tid >> 6, lane = tid & 63;
    __shared__ u16 A_lds[2 * 32 * N];        // [t][f(24)][64][8] frag-packed (48 KB)
    __shared__ float red[2][4][32];
    u16* A0 = A_lds;
    u16* A1 = A_lds + 32 * N;
    const u16* Zh = Zbf + h * (N * N);
    const float* Yh = Y + h * (N * N);       // Y[k][i]
    const float* vjd0 = vjT + h * (D * N) + d0 * N;
    const float* vjd1 = vjT + h * (D * N) + d1 * N;
    const float* vkd0 = vkT + h * (D * N) + d0 * N;
    const float* vkd1 = vkT + h * (D * N) + d1 * N;

    // ---- A-prep: coalesced global reads, frag-packed LDS writes (both tiles)
    {
#pragma unroll
        for (int it = 0; it < 6; ++it) {
            const int g = it * 256 + tid;        // 0..1535
            const int row = g / 48;              // 0..31
            const int cb = g - row * 48;
            const int jb = cb * 8;
            const int fi = row >> 4, l15r = row & 15;
            const int js = cb >> 2, sub = cb & 3;
            const int f = fi * 12 + js;          // 0..23
            const int dst = f * 512 + (((l15r | (sub << 4)) ^ (f & 7)) << 3);
            short8 zv = *(const short8*)&Zh[(i0 + row) * N + jb];
            if (dgden) {
                *(short8*)&A0[dst] = zv;
                *(short8*)&A1[dst] = zv;
            } else {
                float4 p0 = *(const float4*)&vjd0[jb];
                float4 p1 = *(const float4*)&vjd0[jb + 4];
                float4 q0 = *(const float4*)&vjd1[jb];
                float4 q1 = *(const float4*)&vjd1[jb + 4];
                float v0[8] = {p0.x, p0.y, p0.z, p0.w, p1.x, p1.y, p1.z, p1.w};
                float v1[8] = {q0.x, q0.y, q0.z, q0.w, q1.x, q1.y, q1.z, q1.w};
                short8 o0, o1;
#pragma unroll
                for (int e = 0; e < 8; ++e) {
                    float zf = bf2f((u16)zv[e]);
                    o0[e] = (short)f2bf(zf * v0[e]);
                    o1[e] = (short)f2bf(zf * v1[e]);
                }
                *(short8*)&A0[dst] = o0;
                *(short8*)&A1[dst] = o1;
            }
        }
    }
    __syncthreads();

    // ---- MFMA main loop: no barriers, k held in accumulators
    f32x4 acc0[2][6], acc1[2][6];
#pragma unroll
    for (int fi = 0; fi < 2; ++fi)
#pragma unroll
        for (int fk = 0; fk < 6; ++fk) {
            acc0[fi][fk] = (f32x4){0.f, 0.f, 0.f, 0.f};
            acc1[fi][fk] = (f32x4){0.f, 0.f, 0.f, 0.f};
        }

    const int l15 = lane & 15;
    const u16* Bp = Xbf + ((h * 24 + w * 6) * 12 << 9) + lane * 8;
    const int KTS = 12 * 512;         // k-tile stride (u16)

#pragma unroll
    for (int js = 0; js < 12; ++js) {
        short8 a0[2], a1[2];
#pragma unroll
        for (int fi = 0; fi < 2; ++fi) {
            const int f = fi * 12 + js;
            const int off = f * 512 + ((lane ^ (f & 7)) << 3);
            a0[fi] = *(const short8*)&A0[off];
            a1[fi] = *(const short8*)&A1[off];
        }
        short8 b[6];
#pragma unroll
        for (int fk = 0; fk < 6; ++fk)
            b[fk] = *(const short8*)&Bp[fk * KTS + js * 512];
        __builtin_amdgcn_s_setprio(1);
#pragma unroll
        for (int fk = 0; fk < 6; ++fk) {
#pragma unroll
            for (int fi = 0; fi < 2; ++fi) {
                acc0[fi][fk] = __builtin_amdgcn_mfma_f32_16x16x32_bf16(a0[fi], b[fk], acc0[fi][fk], 0, 0, 0);
                acc1[fi][fk] = __builtin_amdgcn_mfma_f32_16x16x32_bf16(a1[fi], b[fk], acc1[fi][fk], 0, 0, 0);
            }
        }
        __builtin_amdgcn_s_setprio(0);
    }

    // ---- epilogue (merged d0/d1): Y[k][i] contiguous float4 loads, weight, k-reduce
    const int rbase = (lane >> 4) << 2;
    float np0[2][4], np1[2][4];
#pragma unroll
    for (int fi = 0; fi < 2; ++fi)
#pragma unroll
        for (int reg = 0; reg < 4; ++reg) { np0[fi][reg] = 0.f; np1[fi][reg] = 0.f; }
#pragma unroll
    for (int fk = 0; fk < 6; ++fk) {
        const int kcol = w * 96 + fk * 16 + l15;
        const float vk0 = dgden ? 1.0f : vkd0[kcol];
        const float vk1 = dgden ? 1.0f : vkd1[kcol];
#pragma unroll
        for (int fi = 0; fi < 2; ++fi) {
            const float4 yv = *(const float4*)&Yh[kcol * N + i0 + fi * 16 + rbase];
            const float yarr[4] = {yv.x, yv.y, yv.z, yv.w};
#pragma unroll
            for (int reg = 0; reg < 4; ++reg) {
                np0[fi][reg] = fmaf(acc0[fi][fk][reg], yarr[reg] * vk0, np0[fi][reg]);
                np1[fi][reg] = fmaf(acc1[fi][fk][reg], yarr[reg] * vk1, np1[fi][reg]);
            }
        }
    }
#pragma unroll
    for (int fi = 0; fi < 2; ++fi) {
#pragma unroll
        for (int reg = 0; reg < 4; ++reg) {
            float v0 = np0[fi][reg];
            v0 += __shfl_xor(v0, 1); v0 += __shfl_xor(v0, 2);
            v0 += __shfl_xor(v0, 4); v0 += __shfl_xor(v0, 8);
            np0[fi][reg] = v0;
            float v1 = np1[fi][reg];
            v1 += __shfl_xor(v1, 1); v1 += __shfl_xor(v1, 2);
            v1 += __shfl_xor(v1, 4); v1 += __shfl_xor(v1, 8);
            np1[fi][reg] = v1;
        }
    }
    if (l15 == 0) {
#pragma unroll
        for (int fi = 0; fi < 2; ++fi)
#pragma unroll
            for (int reg = 0; reg < 4; ++reg) {
                red[0][w][fi * 16 + rbase + reg] = np0[fi][reg];
                red[1][w][fi * 16 + rbase + reg] = np1[fi][reg];
            }
    }
    __syncthreads();
    if (tid < 32) {
        float s = 0.f;
#pragma unroll
        for (int ww = 0; ww < 4; ++ww) s += red[0][ww][tid];
        if (!dgden) NumB[h * (N * D) + (i0 + tid) * D + 2 * dg] = s;
        else        DenB[h * N + i0 + tid] = s;
    } else if (tid < 64 && !dgden) {
        const int i = tid - 32;
        float s = 0.f;
#pragma unroll
        for (int ww = 0; ww < 4; ++ww) s += red[1][ww][i];
        NumB[h * (N * D) + (i0 + i) * D + 2 * dg + 1] = s;
    }
}

// ---------------- K4: normalize + fp32 output [n, h*D+d] ----------------
__global__ void out_kernel(const float* __restrict__ NumB, const float* __restrict__ DenB,
                           float* __restrict__ out) {
    int idx = blockIdx.x * 256 + threadIdx.x;  // 0..98303
    int n = idx >> 8;
    int ch = idx & 255;
    int hh = ch >> 5, d = ch & 31;
    float v = NumB[hh * (N * D) + n * D + d] / (DenB[hh * N + n] + EPS);
    out[idx] = v;
}

extern "C" void kernel_launch(void* const* d_in, const int* in_sizes, int n_in,
                              void* d_out, int out_size, void* d_ws, size_t ws_size,
                              hipStream_t stream) {
    const float* hs = (const float*)d_in[0];
    const float* W  = (const float*)d_in[1];
    float* ws = (float*)d_ws;
    float* Yp    = ws + S_OFF + HNN;   // plane 1 of the old S buffer: Y[k][i]
    float* projT = ws + VJT_OFF;       // vj rows, then vk rows at +H*D*N
    float* NumB  = ws + NUM_OFF;
    float* DenB  = ws + DEN_OFF;
    u16*   Xbf   = (u16*)(ws + XBF_OFF);
    u16*   Zbf   = (u16*)(ws + ZBF_OFF);
    u16*   Lbf   = (u16*)(ws + LBF_OFF);
    float* out = (float*)d_out;

    proj_kernel<<<dim3(20, 6), 256, 0, stream>>>(hs, W, projT, Lbf);
    scores_mfma<<<dim3(9, 8, 3), 256, 0, stream>>>(Lbf, Yp, Xbf, Zbf);
    cubic_mfma<<<dim3(1632), 256, 0, stream>>>(Xbf, Zbf, Yp, ws + VJT_OFF,
                                               ws + VKT_OFF, NumB, DenB);
    out_kernel<<<(H * N * D) / 256, 256, 0, stream>>>(NumB, DenB, out);
}